// Round 6
// baseline (19154.668 us; speedup 1.0000x reference)
//
#include <hip/hip_runtime.h>
#include <hip/hip_fp16.h>

#define T_STEPS 4096
#define RES     4096
#define NIN     64
#define NOUT    32
#define NWG     256
#define TPB     512   // 8 waves; 2 rows/wave

typedef unsigned long long ull;

// Published x values are encoded as x+2.0 (range (1,3)); 0.0 = not written.
__device__ __forceinline__ bool rdy(ull q) {
    return (__uint_as_float((unsigned)q) > 0.5f) &&
           (__uint_as_float((unsigned)(q >> 32)) > 0.5f);
}

__global__ void esn_init(float* __restrict__ Xf) {
    int i = blockIdx.x * 256 + threadIdx.x;
    if (i < RES) Xf[i] = 2.0f;                 // encoded x[0] = 0
}

// ---------------------------------------------------------------------------
// Persistent recurrence. 256 WGs x 512 thr; WG g owns rows g*16..g*16+15.
// ROUNDS 2-5 POST-MORTEM: the allocator refuses to keep a big W live-range in
// VGPRs (remat round 2/4, spill round 5; 64 MB/step re-streamed from L2/LLC =
// the whole 13-34 ms). Fix: W lives in LDS as fp16 (16 rows x 4096 x 2 B =
// 128 KiB of the 160 KiB), converted once from HBM. LDS is explicitly
// addressed - the compiler cannot evict it. fp16 quantization of W (entries
// +-0.045) adds ~3e-3 to the output, negligible vs the 0.25 threshold.
// Sync: data-as-flag (encoded x in fresh row Xf[t], relaxed agent-scope).
// ---------------------------------------------------------------------------
__global__ __launch_bounds__(TPB, 2)
void esn_recur(const float* __restrict__ inp,
               const float* __restrict__ Win,
               const float* __restrict__ W,
               float* __restrict__ Xf)          // [T][RES], encoded
{
    __shared__ __half Wl[16][RES];              // 128 KiB fp16 W tile
    __shared__ float  xs[RES];                  // 16 KiB staged x[t-1]

    const int g    = blockIdx.x;
    const int tid  = threadIdx.x;
    const int wv   = tid >> 6;
    const int lane = tid & 63;
    const int r0   = g * 16 + wv * 2;

    // ---- stage W -> LDS fp16 (once; 256 KB coalesced read per WG) --------
    {
        const float4* Wg = (const float4*)(W + (size_t)g * 16 * RES);
        for (int idx = tid; idx < 16 * RES / 4; idx += TPB) {
            float4 v  = Wg[idx];
            int  row  = idx >> 10;
            int  c4   = (idx & 1023) * 4;
            Wl[row][c4 + 0] = __float2half_rn(v.x);
            Wl[row][c4 + 1] = __float2half_rn(v.y);
            Wl[row][c4 + 2] = __float2half_rn(v.z);
            Wl[row][c4 + 3] = __float2half_rn(v.w);
        }
    }

    const float win0 = Win[(size_t)(r0 + 0) * NIN + lane];
    const float win1 = Win[(size_t)(r0 + 1) * NIN + lane];
    float u = inp[NIN + lane];                  // u for t=1

    __syncthreads();                            // W tile ready

    const __half2* wr0 = (const __half2*)&Wl[2 * wv][0];
    const __half2* wr1 = (const __half2*)&Wl[2 * wv + 1][0];

    for (int t = 1; t < T_STEPS; ++t) {
        // ---- poll my 32 B of x[t-1]; reload only missing chunks ----------
        const ull* src = (const ull*)(Xf + (size_t)(t - 1) * RES) + tid * 4;
        ull q0 = 0, q1 = 0, q2 = 0, q3 = 0;
        int need = 15;
        do {
            if (need & 1) { q0 = __hip_atomic_load(src + 0, __ATOMIC_RELAXED, __HIP_MEMORY_SCOPE_AGENT); if (rdy(q0)) need &= ~1; }
            if (need & 2) { q1 = __hip_atomic_load(src + 1, __ATOMIC_RELAXED, __HIP_MEMORY_SCOPE_AGENT); if (rdy(q1)) need &= ~2; }
            if (need & 4) { q2 = __hip_atomic_load(src + 2, __ATOMIC_RELAXED, __HIP_MEMORY_SCOPE_AGENT); if (rdy(q2)) need &= ~4; }
            if (need & 8) { q3 = __hip_atomic_load(src + 3, __ATOMIC_RELAXED, __HIP_MEMORY_SCOPE_AGENT); if (rdy(q3)) need &= ~8; }
        } while (need);

        __syncthreads();                        // prev step done reading xs

        float* dst = &xs[tid * 8];
        ((float4*)dst)[0] = make_float4(
            __uint_as_float((unsigned)q0)         - 2.0f,
            __uint_as_float((unsigned)(q0 >> 32)) - 2.0f,
            __uint_as_float((unsigned)q1)         - 2.0f,
            __uint_as_float((unsigned)(q1 >> 32)) - 2.0f);
        ((float4*)dst)[1] = make_float4(
            __uint_as_float((unsigned)q2)         - 2.0f,
            __uint_as_float((unsigned)(q2 >> 32)) - 2.0f,
            __uint_as_float((unsigned)q3)         - 2.0f,
            __uint_as_float((unsigned)(q3 >> 32)) - 2.0f);

        float ucur = u;
        if (t + 1 < T_STEPS) u = inp[(size_t)(t + 1) * NIN + lane];

        __syncthreads();                        // xs fully staged

        // ---- a = W_in u_t + W x_{t-1} (2 rows/wave, fp16 W from LDS) ------
        float a0 = win0 * ucur, a1 = win1 * ucur;
        const float4* xv = (const float4*)&xs[4 * lane];
#pragma unroll
        for (int c = 0; c < 16; ++c) {
            float4 x4 = xv[64 * c];
            int cb = 2 * lane + 128 * c;        // half2 index, 8B-aligned pair
            __half2 p0 = wr0[cb], p1 = wr0[cb + 1];
            __half2 r1 = wr1[cb], r2 = wr1[cb + 1];
            float2 f0 = __half22float2(p0), f1 = __half22float2(p1);
            float2 g0 = __half22float2(r1), g1 = __half22float2(r2);
            a0 += f0.x * x4.x + f0.y * x4.y + f1.x * x4.z + f1.y * x4.w;
            a1 += g0.x * x4.x + g0.y * x4.y + g1.x * x4.z + g1.y * x4.w;
        }
#pragma unroll
        for (int off = 32; off > 0; off >>= 1) {
            a0 += __shfl_xor(a0, off, 64);
            a1 += __shfl_xor(a1, off, 64);
        }

        if (lane < 2) {
            float s  = lane ? a1 : a0;
            float xn = tanhf(s);
            // fire-and-forget publish; the value itself is the ready flag
            __hip_atomic_store(Xf + (size_t)t * RES + r0 + lane, xn + 2.0f,
                               __ATOMIC_RELAXED, __HIP_MEMORY_SCOPE_AGENT);
        }
    }
}

// ---------------------------------------------------------------------------
// Readout: out[T,32] = decode(Xf) @ W_out. 2 t-rows/block.
// ---------------------------------------------------------------------------
__global__ __launch_bounds__(256)
void esn_out(const float* __restrict__ Xf,
             const float* __restrict__ Wout,
             float* __restrict__ out)
{
    __shared__ float xs[2 * RES];
    __shared__ float red[2][8][32];
    const int tid = threadIdx.x;
    const int t0  = blockIdx.x * 2;

    const float4* s4 = (const float4*)(Xf + (size_t)t0 * RES);
    float4*       d4 = (float4*)xs;
    for (int i = tid; i < 2 * RES / 4; i += 256) {
        float4 v = s4[i];
        v.x -= 2.0f; v.y -= 2.0f; v.z -= 2.0f; v.w -= 2.0f;   // decode
        d4[i] = v;
    }
    __syncthreads();

    const int o  = tid & 31;
    const int sg = tid >> 5;
    float acc0 = 0.f, acc1 = 0.f;
    const int rbeg = sg * 512;
    for (int r = rbeg; r < rbeg + 512; ++r) {
        float wv = Wout[(size_t)r * NOUT + o];
        acc0 += xs[r] * wv;
        acc1 += xs[RES + r] * wv;
    }
    red[0][sg][o] = acc0;
    red[1][sg][o] = acc1;
    __syncthreads();

    if (tid < 64) {
        const int h = tid >> 5, oo = tid & 31;
        float s = 0.f;
#pragma unroll
        for (int k = 0; k < 8; ++k) s += red[h][k][oo];
        out[(size_t)(t0 + h) * NOUT + oo] = s;
    }
}

// ---------------------------------------------------------------------------
extern "C" void kernel_launch(void* const* d_in, const int* in_sizes, int n_in,
                              void* d_out, int out_size, void* d_ws, size_t ws_size,
                              hipStream_t stream)
{
    const float* inputs = (const float*)d_in[0];   // [T, 64]
    const float* W_in   = (const float*)d_in[1];   // [RES, 64]
    const float* W      = (const float*)d_in[2];   // [RES, RES]
    const float* W_out  = (const float*)d_in[3];   // [RES, 32]
    float* out = (float*)d_out;                    // [T, 32]

    float* Xf = (float*)d_ws;                      // [T][RES] encoded, 64 MiB

    // Replay-safe: zero the whole history (0.0 = "not written"), re-encode
    // row 0. Graph-capturable (async memset + kernels only).
    hipMemsetAsync(Xf, 0, (size_t)T_STEPS * RES * sizeof(float), stream);
    esn_init<<<dim3((RES + 255) / 256), dim3(256), 0, stream>>>(Xf);

    esn_recur<<<dim3(NWG), dim3(TPB), 0, stream>>>(inputs, W_in, W, Xf);
    esn_out<<<dim3(T_STEPS / 2), dim3(256), 0, stream>>>(Xf, W_out, out);
}

// Round 7
// 12021.515 us; speedup vs baseline: 1.5934x; 1.5934x over previous
//
#include <hip/hip_runtime.h>
#include <hip/hip_fp16.h>

#define T_STEPS 4096
#define RES     4096
#define NIN     64
#define NOUT    32
#define NWG     256
#define TPB     512   // 8 waves
#define WS      4168  // halfs per W row in LDS: 4096 W + 64 W_in + 8 pad (bank skew)

typedef unsigned long long ull;
typedef _Float16 h2 __attribute__((ext_vector_type(2)));

// Published x values are encoded as x+2.0 (range (1,3)); 0.0 = not written.
__device__ __forceinline__ bool rdy(ull q) {
    return (__uint_as_float((unsigned)q) > 0.5f) &&
           (__uint_as_float((unsigned)(q >> 32)) > 0.5f);
}

__device__ __forceinline__ float dot8(uint4 wq, uint4 xq, float acc) {
    acc = __builtin_amdgcn_fdot2(__builtin_bit_cast(h2, wq.x), __builtin_bit_cast(h2, xq.x), acc, false);
    acc = __builtin_amdgcn_fdot2(__builtin_bit_cast(h2, wq.y), __builtin_bit_cast(h2, xq.y), acc, false);
    acc = __builtin_amdgcn_fdot2(__builtin_bit_cast(h2, wq.z), __builtin_bit_cast(h2, xq.z), acc, false);
    acc = __builtin_amdgcn_fdot2(__builtin_bit_cast(h2, wq.w), __builtin_bit_cast(h2, xq.w), acc, false);
    return acc;
}

__global__ void esn_init(float* __restrict__ Xf) {
    int i = blockIdx.x * 256 + threadIdx.x;
    if (i < RES) Xf[i] = 2.0f;                 // encoded x[0] = 0
}

// ---------------------------------------------------------------------------
// Persistent recurrence. 256 WGs x 512 thr; WG g owns rows g*16..g*16+15.
// W (+W_in as 64 extra cols) lives in LDS fp16, row stride 4168 halfs.
// COLUMN-SPLIT (round-6 post-mortem: full-x-per-wave was 2x LDS traffic and
// 3x LDS instrs): wave wv owns cols [512wv,512wv+512) of ALL 16 rows; lane
// (cg=lane>>4, r=lane&15) computes row r over 128 cols as 16 ds_read_b128 +
// 64 v_dot2_f32_f16 (f32 accum). cg==0 lanes take the 8 u-cols at 4096+8wv.
// Partials -> red[16][33] -> barrier -> wave 0 reduces, tanh, publishes.
// Sync: data-as-flag (encoded x in fresh row Xf[t], relaxed agent-scope).
// ---------------------------------------------------------------------------
__global__ __launch_bounds__(TPB, 1)
void esn_recur(const float* __restrict__ inp,
               const float* __restrict__ Win,
               const float* __restrict__ W,
               float* __restrict__ Xf)          // [T][RES], encoded
{
    __shared__ __align__(16) __half Wl[16 * WS];   // 130.25 KiB
    __shared__ __align__(16) __half xh[RES + NIN]; // 8.125 KiB (x + u, fp16)
    __shared__ float red[16 * 33];                 // 2.06 KiB (padded 16x32)

    const int g    = blockIdx.x;
    const int tid  = threadIdx.x;
    const int wv   = tid >> 6;
    const int lane = tid & 63;

    // ---- stage W -> LDS fp16 (once; coalesced 256 KB read per WG) ---------
    {
        const float4* Wg = (const float4*)(W + (size_t)g * 16 * RES);
        for (int idx = tid; idx < 16 * RES / 4; idx += TPB) {
            float4 v  = Wg[idx];
            int  row  = idx >> 10;
            int  c    = (idx & 1023) * 4;
            __half* d = &Wl[row * WS + c];
            d[0] = __float2half_rn(v.x);
            d[1] = __float2half_rn(v.y);
            d[2] = __float2half_rn(v.z);
            d[3] = __float2half_rn(v.w);
        }
        for (int idx = tid; idx < 16 * NIN; idx += TPB) {
            int row = idx >> 6, k = idx & 63;
            Wl[row * WS + RES + k] = __float2half_rn(Win[(size_t)(g * 16 + row) * NIN + k]);
        }
    }

    float u_cur = 0.f;
    if (tid < NIN) u_cur = inp[NIN + tid];     // u for t=1

    __syncthreads();                           // W tile ready

    const uint4* WQ = (const uint4*)Wl;
    const uint4* XQ = (const uint4*)xh;
    const int r  = lane & 15;
    const int cg = lane >> 4;
    const int wb = r * (WS / 8) + wv * 64 + cg * 16;   // uint4 units
    const int xb = wv * 64 + cg * 16;

    for (int t = 1; t < T_STEPS; ++t) {
        // ---- poll my 32 B of x[t-1]; reload only missing chunks ----------
        const ull* src = (const ull*)(Xf + (size_t)(t - 1) * RES) + tid * 4;
        ull q0 = 0, q1 = 0, q2 = 0, q3 = 0;
        int need = 15;
        do {
            if (need & 1) { q0 = __hip_atomic_load(src + 0, __ATOMIC_RELAXED, __HIP_MEMORY_SCOPE_AGENT); if (rdy(q0)) need &= ~1; }
            if (need & 2) { q1 = __hip_atomic_load(src + 1, __ATOMIC_RELAXED, __HIP_MEMORY_SCOPE_AGENT); if (rdy(q1)) need &= ~2; }
            if (need & 4) { q2 = __hip_atomic_load(src + 2, __ATOMIC_RELAXED, __HIP_MEMORY_SCOPE_AGENT); if (rdy(q2)) need &= ~4; }
            if (need & 8) { q3 = __hip_atomic_load(src + 3, __ATOMIC_RELAXED, __HIP_MEMORY_SCOPE_AGENT); if (rdy(q3)) need &= ~8; }
        } while (need);

        // ---- stage my 8 x-values (decode, cvt fp16) + u slice -------------
        {
            __half hv[8];
            hv[0] = __float2half_rn(__uint_as_float((unsigned)q0)         - 2.0f);
            hv[1] = __float2half_rn(__uint_as_float((unsigned)(q0 >> 32)) - 2.0f);
            hv[2] = __float2half_rn(__uint_as_float((unsigned)q1)         - 2.0f);
            hv[3] = __float2half_rn(__uint_as_float((unsigned)(q1 >> 32)) - 2.0f);
            hv[4] = __float2half_rn(__uint_as_float((unsigned)q2)         - 2.0f);
            hv[5] = __float2half_rn(__uint_as_float((unsigned)(q2 >> 32)) - 2.0f);
            hv[6] = __float2half_rn(__uint_as_float((unsigned)q3)         - 2.0f);
            hv[7] = __float2half_rn(__uint_as_float((unsigned)(q3 >> 32)) - 2.0f);
            ((uint4*)xh)[tid] = *(const uint4*)hv;
        }
        if (tid < NIN) {
            xh[RES + tid] = __float2half_rn(u_cur);
            if (t + 1 < T_STEPS) u_cur = inp[(size_t)(t + 1) * NIN + tid];
        }

        __syncthreads();                       // xh fully staged

        // ---- partial dot: row r, cols [512wv+128cg, +128) (+u if cg==0) ---
        float acc = 0.f;
#pragma unroll
        for (int i = 0; i < 16; ++i)
            acc = dot8(WQ[wb + i], XQ[xb + i], acc);
        if (cg == 0)
            acc = dot8(WQ[r * (WS / 8) + RES / 8 + wv], XQ[RES / 8 + wv], acc);
        red[r * 33 + wv * 4 + cg] = acc;

        __syncthreads();                       // red complete

        // ---- wave 0: reduce 32 partials/row, tanh, publish ----------------
        if (wv == 0) {
            const int rr = lane >> 2, q = lane & 3;
            const float* rp = &red[rr * 33 + 8 * q];
            float s = ((rp[0] + rp[1]) + (rp[2] + rp[3])) +
                      ((rp[4] + rp[5]) + (rp[6] + rp[7]));
            s += __shfl_xor(s, 1, 64);
            s += __shfl_xor(s, 2, 64);
            if (q == 0) {
                float xn = tanhf(s);
                __hip_atomic_store(Xf + (size_t)t * RES + g * 16 + rr, xn + 2.0f,
                                   __ATOMIC_RELAXED, __HIP_MEMORY_SCOPE_AGENT);
            }
        }
        // next iteration's xh/red writes are fenced by the two barriers above
    }
}

// ---------------------------------------------------------------------------
// Readout: out[T,32] = decode(Xf) @ W_out. 2 t-rows/block.
// ---------------------------------------------------------------------------
__global__ __launch_bounds__(256)
void esn_out(const float* __restrict__ Xf,
             const float* __restrict__ Wout,
             float* __restrict__ out)
{
    __shared__ float xs[2 * RES];
    __shared__ float red[2][8][32];
    const int tid = threadIdx.x;
    const int t0  = blockIdx.x * 2;

    const float4* s4 = (const float4*)(Xf + (size_t)t0 * RES);
    float4*       d4 = (float4*)xs;
    for (int i = tid; i < 2 * RES / 4; i += 256) {
        float4 v = s4[i];
        v.x -= 2.0f; v.y -= 2.0f; v.z -= 2.0f; v.w -= 2.0f;   // decode
        d4[i] = v;
    }
    __syncthreads();

    const int o  = tid & 31;
    const int sg = tid >> 5;
    float acc0 = 0.f, acc1 = 0.f;
    const int rbeg = sg * 512;
    for (int rr = rbeg; rr < rbeg + 512; ++rr) {
        float wv = Wout[(size_t)rr * NOUT + o];
        acc0 += xs[rr] * wv;
        acc1 += xs[RES + rr] * wv;
    }
    red[0][sg][o] = acc0;
    red[1][sg][o] = acc1;
    __syncthreads();

    if (tid < 64) {
        const int h = tid >> 5, oo = tid & 31;
        float s = 0.f;
#pragma unroll
        for (int k = 0; k < 8; ++k) s += red[h][k][oo];
        out[(size_t)(t0 + h) * NOUT + oo] = s;
    }
}

// ---------------------------------------------------------------------------
extern "C" void kernel_launch(void* const* d_in, const int* in_sizes, int n_in,
                              void* d_out, int out_size, void* d_ws, size_t ws_size,
                              hipStream_t stream)
{
    const float* inputs = (const float*)d_in[0];   // [T, 64]
    const float* W_in   = (const float*)d_in[1];   // [RES, 64]
    const float* W      = (const float*)d_in[2];   // [RES, RES]
    const float* W_out  = (const float*)d_in[3];   // [RES, 32]
    float* out = (float*)d_out;                    // [T, 32]

    float* Xf = (float*)d_ws;                      // [T][RES] encoded, 64 MiB

    // Replay-safe: zero the whole history (0.0 = "not written"), re-encode
    // row 0. Graph-capturable (async memset + kernels only).
    hipMemsetAsync(Xf, 0, (size_t)T_STEPS * RES * sizeof(float), stream);
    esn_init<<<dim3((RES + 255) / 256), dim3(256), 0, stream>>>(Xf);

    esn_recur<<<dim3(NWG), dim3(TPB), 0, stream>>>(inputs, W_in, W, Xf);
    esn_out<<<dim3(T_STEPS / 2), dim3(256), 0, stream>>>(Xf, W_out, out);
}

// Round 8
// 11863.660 us; speedup vs baseline: 1.6146x; 1.0133x over previous
//
#include <hip/hip_runtime.h>
#include <hip/hip_fp16.h>

#define T_STEPS 4096
#define RES     4096
#define NIN     64
#define NOUT    32
#define NWG     256
#define TPB     512           // 8 waves
#define WS      4168          // halfs per W row in LDS: 4096 W + 64 W_in + 8 pad
#define WR      (WS / 8)      // 521 uint4 per row

typedef unsigned long long ull;
typedef _Float16 hv2 __attribute__((ext_vector_type(2)));

__device__ __forceinline__ float dot8(uint4 wq, uint4 xq, float acc) {
    acc = __builtin_amdgcn_fdot2(__builtin_bit_cast(hv2, wq.x), __builtin_bit_cast(hv2, xq.x), acc, false);
    acc = __builtin_amdgcn_fdot2(__builtin_bit_cast(hv2, wq.y), __builtin_bit_cast(hv2, xq.y), acc, false);
    acc = __builtin_amdgcn_fdot2(__builtin_bit_cast(hv2, wq.z), __builtin_bit_cast(hv2, xq.z), acc, false);
    acc = __builtin_amdgcn_fdot2(__builtin_bit_cast(hv2, wq.w), __builtin_bit_cast(hv2, xq.w), acc, false);
    return acc;
}

// all 4 encoded halfs nonzero? (published x+2 is in (1,3): never 0x0000)
__device__ __forceinline__ bool ok4(ull q) {
    return ((unsigned short)q) && ((unsigned short)(q >> 16)) &&
           ((unsigned short)(q >> 32)) && ((unsigned short)(q >> 48));
}

// packed fp16 pair: (enc - 2.0) exactly (grid 2^-10 in (1,3) maps onto fp16 grid in (-1,1))
__device__ __forceinline__ unsigned sub2(unsigned u) {
    __half2 h = *(__half2*)&u;
    __half2 r = __hsub2(h, __floats2half2_rn(2.f, 2.f));
    return *(unsigned*)&r;
}

__global__ void esn_init(unsigned short* __restrict__ Xh) {
    int i = blockIdx.x * 256 + threadIdx.x;
    if (i < RES) Xh[i] = 0x4000;               // half(2.0) == encoded x[0] = 0
}

// ---------------------------------------------------------------------------
// Persistent recurrence. 256 WGs x 512 thr; WG g owns rows 16g..16g+15.
// W (+W_in cols) in LDS fp16 (proven r6/r7). ROUND-7 POST-MORTEM fixes:
//  - x published as fp16 (x+2, 0=unwritten): halves all LLC poll traffic.
//  - per-wave slices: wave wv polls ONLY its 1 KB of x[t-1] (data-as-flag on
//    exactly the consumed bytes) -> no global all-ready convoy.
//  - W chunks prefetched into 64 VGPRs BEFORE the poll (lgkmcnt+mem-clobber
//    pins them): W-read latency hides under the spin.
//  - chunk rotation j=(i+4cg)&15 on W and x: W banks balanced-8, x 2-way.
//  - distributed reduce: wave wv reduces rows 2wv,2wv+1, publishes one 4 B
//    atomic (16 halfs/WG across 8 stores); red[] parity-double-buffered ->
//    ONE __syncthreads per step.
// ---------------------------------------------------------------------------
__global__ __launch_bounds__(TPB, 1)
void esn_recur(const float* __restrict__ inp,
               const float* __restrict__ Win,
               const float* __restrict__ W,
               unsigned short* __restrict__ Xh)   // [T][RES] fp16 encoded
{
    __shared__ __align__(16) __half Wl[16 * WS];   // 130.25 KiB
    __shared__ __align__(16) __half xh[RES + NIN]; // 8.125 KiB (fp16 x + u)
    __shared__ float red[2][16][33];               // 4.125 KiB, parity dbuf

    const int g    = blockIdx.x;
    const int tid  = threadIdx.x;
    const int wv   = tid >> 6;
    const int lane = tid & 63;
    const int r    = lane & 15;      // row within the 16-row tile
    const int cg   = lane >> 4;      // column group 0..3

    // ---- stage W -> LDS fp16 (once) + W_in as cols 4096..4159 -------------
    {
        const float4* Wg = (const float4*)(W + (size_t)g * 16 * RES);
        for (int idx = tid; idx < 16 * RES / 4; idx += TPB) {
            float4 v  = Wg[idx];
            int  row  = idx >> 10;
            int  c    = (idx & 1023) * 4;
            __half* d = &Wl[row * WS + c];
            d[0] = __float2half_rn(v.x);
            d[1] = __float2half_rn(v.y);
            d[2] = __float2half_rn(v.z);
            d[3] = __float2half_rn(v.w);
        }
        for (int idx = tid; idx < 16 * NIN; idx += TPB) {
            int row = idx >> 6, k = idx & 63;
            Wl[row * WS + RES + k] = __float2half_rn(Win[(size_t)(g * 16 + row) * NIN + k]);
        }
    }

    float u_cur = (wv == 0) ? inp[NIN + lane] : 0.f;   // u for t=1 (wave 0)

    __syncthreads();                                   // W tile ready

    const uint4* WQ    = (const uint4*)Wl;
    const uint4* XQ    = (const uint4*)xh;
    const int    wbase = r * WR + wv * 64 + 16 * cg;   // uint4 units
    const int    xbase = wv * 64 + 16 * cg;

    for (int t = 1; t < T_STEPS; ++t) {
        // ---- prefetch W chunks into regs; latency hides under the poll ----
        uint4 wq[16];
#pragma unroll
        for (int i = 0; i < 16; ++i)
            wq[i] = WQ[wbase + ((i + 4 * cg) & 15)];
        uint4 wu0, wu1;
        if (wv == 0) {                                  // u-projection cols
            wu0 = WQ[r * WR + 512 + 2 * cg];
            wu1 = WQ[r * WR + 513 + 2 * cg];
        }
        asm volatile("s_waitcnt lgkmcnt(0)" ::: "memory");  // pin reads before spin

        // ---- poll ONLY my wave's 16 B of x[t-1] (data-as-flag) ------------
        const ull* src = (const ull*)(Xh + (size_t)(t - 1) * RES) + 128 * wv + 2 * lane;
        ull q0 = 0, q1 = 0;
        int need = 3;
        do {
            if (need & 1) { q0 = __hip_atomic_load(src,     __ATOMIC_RELAXED, __HIP_MEMORY_SCOPE_AGENT); if (ok4(q0)) need &= ~1; }
            if (need & 2) { q1 = __hip_atomic_load(src + 1, __ATOMIC_RELAXED, __HIP_MEMORY_SCOPE_AGENT); if (ok4(q1)) need &= ~2; }
        } while (need);

        // ---- stage decoded slice (one b128 write; slice is wave-private) --
        uint4 sv;
        sv.x = sub2((unsigned)q0); sv.y = sub2((unsigned)(q0 >> 32));
        sv.z = sub2((unsigned)q1); sv.w = sub2((unsigned)(q1 >> 32));
        *(uint4*)(xh + 512 * wv + 8 * lane) = sv;
        if (wv == 0) xh[RES + lane] = __float2half_rn(u_cur);
        asm volatile("s_waitcnt lgkmcnt(0)" ::: "memory");  // wave-local LDS visible

        // ---- partial dot: row r, cols [512wv+128cg, +128) -----------------
        float acc = 0.f;
#pragma unroll
        for (int i = 0; i < 16; ++i) {
            uint4 xq = XQ[xbase + ((i + 4 * cg) & 15)];
            acc = dot8(wq[i], xq, acc);
        }
        if (wv == 0) {                                  // + W_in u_t slice
            const uint4* XU = (const uint4*)(xh + RES);
            acc = dot8(wu0, XU[2 * cg], acc);
            acc = dot8(wu1, XU[2 * cg + 1], acc);
            u_cur = (t + 1 < T_STEPS) ? inp[(size_t)(t + 1) * NIN + lane] : 0.f;
        }
        red[t & 1][r][4 * wv + cg] = acc;
        __syncthreads();                                // all partials in red

        // ---- distributed reduce: wave wv -> rows 2wv, 2wv+1; publish ------
        {
            const int row = 2 * wv + (lane >> 5);
            float s = red[t & 1][row][lane & 31];
            s += __shfl_xor(s, 1, 64);
            s += __shfl_xor(s, 2, 64);
            s += __shfl_xor(s, 4, 64);
            s += __shfl_xor(s, 8, 64);
            s += __shfl_xor(s, 16, 64);                 // lanes 0,32 hold sums
            float xn = tanhf(s);
            unsigned enc = (unsigned)__half_as_ushort(__float2half_rn(xn + 2.0f));
            unsigned hi  = (unsigned)__shfl((int)enc, 32, 64);
            if (lane == 0) {
                unsigned pk = enc | (hi << 16);         // rows 2wv, 2wv+1
                __hip_atomic_store((unsigned*)(Xh + (size_t)t * RES + 16 * g + 2 * wv), pk,
                                   __ATOMIC_RELAXED, __HIP_MEMORY_SCOPE_AGENT);
            }
        }
    }
}

// ---------------------------------------------------------------------------
// Readout: out[T,32] = decode(Xh) @ W_out. 2 t-rows/block.
// ---------------------------------------------------------------------------
__global__ __launch_bounds__(256)
void esn_out(const unsigned short* __restrict__ Xh,
             const float* __restrict__ Wout,
             float* __restrict__ out)
{
    __shared__ float xs[2 * RES];
    __shared__ float red[2][8][32];
    const int tid = threadIdx.x;
    const int t0  = blockIdx.x * 2;

    const uint4* s4 = (const uint4*)(Xh + (size_t)t0 * RES);
    for (int i = tid; i < 2 * RES / 8; i += 256) {
        uint4 v  = s4[i];
        float* d = &xs[8 * i];
        float2 f;
        f = __half22float2(*(__half2*)&v.x); d[0] = f.x - 2.f; d[1] = f.y - 2.f;
        f = __half22float2(*(__half2*)&v.y); d[2] = f.x - 2.f; d[3] = f.y - 2.f;
        f = __half22float2(*(__half2*)&v.z); d[4] = f.x - 2.f; d[5] = f.y - 2.f;
        f = __half22float2(*(__half2*)&v.w); d[6] = f.x - 2.f; d[7] = f.y - 2.f;
    }
    __syncthreads();

    const int o  = tid & 31;
    const int sg = tid >> 5;
    float acc0 = 0.f, acc1 = 0.f;
    const int rbeg = sg * 512;
    for (int rr = rbeg; rr < rbeg + 512; ++rr) {
        float wv = Wout[(size_t)rr * NOUT + o];
        acc0 += xs[rr] * wv;
        acc1 += xs[RES + rr] * wv;
    }
    red[0][sg][o] = acc0;
    red[1][sg][o] = acc1;
    __syncthreads();

    if (tid < 64) {
        const int h = tid >> 5, oo = tid & 31;
        float s = 0.f;
#pragma unroll
        for (int k = 0; k < 8; ++k) s += red[h][k][oo];
        out[(size_t)(t0 + h) * NOUT + oo] = s;
    }
}

// ---------------------------------------------------------------------------
extern "C" void kernel_launch(void* const* d_in, const int* in_sizes, int n_in,
                              void* d_out, int out_size, void* d_ws, size_t ws_size,
                              hipStream_t stream)
{
    const float* inputs = (const float*)d_in[0];   // [T, 64]
    const float* W_in   = (const float*)d_in[1];   // [RES, 64]
    const float* W      = (const float*)d_in[2];   // [RES, RES]
    const float* W_out  = (const float*)d_in[3];   // [RES, 32]
    float* out = (float*)d_out;                    // [T, 32]

    unsigned short* Xh = (unsigned short*)d_ws;    // [T][RES] fp16 encoded, 32 MiB

    // Replay-safe: zero history (0x0000 = "not written"), re-encode row 0.
    hipMemsetAsync(Xh, 0, (size_t)T_STEPS * RES * sizeof(unsigned short), stream);
    esn_init<<<dim3((RES + 255) / 256), dim3(256), 0, stream>>>(Xh);

    esn_recur<<<dim3(NWG), dim3(TPB), 0, stream>>>(inputs, W_in, W, Xh);
    esn_out<<<dim3(T_STEPS / 2), dim3(256), 0, stream>>>(Xh, W_out, out);
}